// Round 2
// 294.236 us; speedup vs baseline: 1.0514x; 1.0514x over previous
//
#include <hip/hip_runtime.h>
#include <hip/hip_bf16.h>

typedef __bf16 bf16_t;
typedef bf16_t bf16x8 __attribute__((ext_vector_type(8)));
typedef bf16_t bf16x4 __attribute__((ext_vector_type(4)));
typedef float  f32x4  __attribute__((ext_vector_type(4)));

#define BM 256
#define BN 128
#define BK 64   // one K-tile; a row is 8 chunks of 8 bf16 (16B each)

enum { EPI_NONE = 0, EPI_THRESH = 1, EPI_BIAS = 2 };

__device__ __forceinline__ void memfence() { asm volatile("" ::: "memory"); }
// raw barrier (NO vmcnt drain) with compiler memory fences so LDS ops can't
// be moved across it by the optimizer.
__device__ __forceinline__ void blockbar() {
    memfence(); __builtin_amdgcn_s_barrier(); memfence();
}

#define GLD16(src, dst) __builtin_amdgcn_global_load_lds( \
    (const __attribute__((address_space(1))) void*)(src), \
    (__attribute__((address_space(3))) void*)(dst), 16, 0, 0)

// 256x128 tile, BK=64, 512 threads = 8 waves (4M x 2N), per-wave C = 64x64.
// 3-deep LDS pipeline (144 KiB): compute tile t from buf[t%3] while tile t+1
// is fully in flight and tile t+2 streams into buf[(t+2)%3] -> steady-state
// s_waitcnt vmcnt(6) (6 loads/wave/tile), never 0 in the main loop (T3+T4).
// LDS swizzle: chunk ^= (row&7), applied on the GLOBAL side of
// global_load_lds (LDS stays linear -> satisfies wave-uniform-base rule);
// ds_read_b128 fragments then hit banks at most 2-way (free) -- same scheme
// as the 313us kernel, measured 0 bank conflicts there.
template <int EPI, typename CT>
__device__ __forceinline__
void gemm_tile(const bf16_t* __restrict__ A, const bf16_t* __restrict__ B,
               CT* __restrict__ C, const float* __restrict__ bias,
               int m0, int n0, int N, int K,
               bf16_t* __restrict__ As, bf16_t* __restrict__ Bs)
{
    const int lane = threadIdx.x & 63;
    const int wave = threadIdx.x >> 6;   // 0..7
    const int wm = wave >> 1;            // 0..3: 64-row band of A
    const int wn = wave & 1;             // 0..1: 64-col band of B

    const int fm  = lane & 15;
    const int q   = lane >> 4;
    const int fsw = fm & 7;

    const int NT = K / BK;               // 12 for K=768

    // --- staging slots: each wave issues 6 global_load_lds per K-tile
    // (4 A-slots + 2 B-slots), each covering 64 lanes x 16B = 1 KiB = 8 rows.
    const bf16_t* gsrc[6];
    int ldst[6];                          // element offset inside a buffer
#pragma unroll
    for (int s = 0; s < 6; ++s) {
        const int g = wave + 8 * s;       // 0..47
        if (s < 4) {                      // A: units [0,2048) over 256 rows
            const int u = g * 64 + lane;
            const int row = u >> 3;
            const int ch  = (u & 7) ^ (row & 7);
            gsrc[s] = A + (size_t)(m0 + row) * K + ch * 8;
            ldst[s] = g * 512;
        } else {                          // B: units [0,1024) over 128 rows
            const int u = (g - 32) * 64 + lane;
            const int row = u >> 3;
            const int ch  = (u & 7) ^ (row & 7);
            gsrc[s] = B + (size_t)(n0 + row) * K + ch * 8;
            ldst[s] = (g - 32) * 512;
        }
    }

    f32x4 acc[4][4];
#pragma unroll
    for (int i = 0; i < 4; ++i)
#pragma unroll
        for (int j = 0; j < 4; ++j) acc[i][j] = (f32x4){0.f, 0.f, 0.f, 0.f};

    // --- prologue: stage tile 0 -> buf0, tile 1 -> buf1; wait tile0 only.
#pragma unroll
    for (int s = 0; s < 6; ++s) {
        GLD16(gsrc[s], (s < 4 ? As : Bs) + ldst[s]);
        gsrc[s] += BK;
    }
#pragma unroll
    for (int s = 0; s < 6; ++s) {
        GLD16(gsrc[s], (s < 4 ? As + 256 * 64 : Bs + 128 * 64) + ldst[s]);
        gsrc[s] += BK;
    }
    asm volatile("s_waitcnt vmcnt(6)" ::: "memory");   // tile0 landed
    blockbar();

    int bc = 0;                                        // compute buffer
    for (int t = 0; t < NT; ++t) {
        const bf16_t* __restrict__ Ab = As + bc * (256 * 64);
        const bf16_t* __restrict__ Bb = Bs + bc * (128 * 64);
        const int bs2 = (bc >= 1) ? bc - 1 : 2;        // (bc+2)%3
        bf16_t* Asd = As + bs2 * (256 * 64);
        bf16_t* Bsd = Bs + bs2 * (128 * 64);
        const bool do_stage = (t + 2 < NT);

        bf16x8 af[4][2], bfr[2][2];

        // ---------- phase 1: 12 ds_read + 3 stage + 16 MFMA ----------
#pragma unroll
        for (int i = 0; i < 4; ++i) {
            const int row = wm * 64 + i * 16 + fm;
#pragma unroll
            for (int kk = 0; kk < 2; ++kk)
                af[i][kk] = *(const bf16x8*)(Ab + (size_t)(row * 8 + ((kk * 4 + q) ^ fsw)) * 8);
        }
#pragma unroll
        for (int j = 0; j < 2; ++j) {
            const int row = wn * 64 + j * 16 + fm;
#pragma unroll
            for (int kk = 0; kk < 2; ++kk)
                bfr[j][kk] = *(const bf16x8*)(Bb + (size_t)(row * 8 + ((kk * 4 + q) ^ fsw)) * 8);
        }
        if (do_stage) {
            GLD16(gsrc[0], Asd + ldst[0]); gsrc[0] += BK;
            GLD16(gsrc[1], Asd + ldst[1]); gsrc[1] += BK;
            GLD16(gsrc[4], Bsd + ldst[4]); gsrc[4] += BK;
        }
        blockbar();
        __builtin_amdgcn_s_setprio(1);
#pragma unroll
        for (int i = 0; i < 4; ++i)
#pragma unroll
            for (int j = 0; j < 2; ++j)
#pragma unroll
                for (int kk = 0; kk < 2; ++kk)
                    acc[i][j] = __builtin_amdgcn_mfma_f32_16x16x32_bf16(
                        af[i][kk], bfr[j][kk], acc[i][j], 0, 0, 0);
        __builtin_amdgcn_s_setprio(0);
        blockbar();

        // ---------- phase 2: 4 ds_read + 3 stage + 16 MFMA ----------
#pragma unroll
        for (int j = 0; j < 2; ++j) {
            const int row = wn * 64 + (j + 2) * 16 + fm;
#pragma unroll
            for (int kk = 0; kk < 2; ++kk)
                bfr[j][kk] = *(const bf16x8*)(Bb + (size_t)(row * 8 + ((kk * 4 + q) ^ fsw)) * 8);
        }
        if (do_stage) {
            GLD16(gsrc[2], Asd + ldst[2]); gsrc[2] += BK;
            GLD16(gsrc[3], Asd + ldst[3]); gsrc[3] += BK;
            GLD16(gsrc[5], Bsd + ldst[5]); gsrc[5] += BK;
        }
        blockbar();
        __builtin_amdgcn_s_setprio(1);
#pragma unroll
        for (int i = 0; i < 4; ++i)
#pragma unroll
            for (int j = 0; j < 2; ++j)
#pragma unroll
                for (int kk = 0; kk < 2; ++kk)
                    acc[i][j + 2] = __builtin_amdgcn_mfma_f32_16x16x32_bf16(
                        af[i][kk], bfr[j][kk], acc[i][j + 2], 0, 0, 0);
        __builtin_amdgcn_s_setprio(0);

        if (t < NT - 1) {
            // all of this wave's ds_reads must retire before staging may
            // overwrite a rotated-out buffer behind the barrier
            asm volatile("s_waitcnt lgkmcnt(0)" ::: "memory");
            if (do_stage) asm volatile("s_waitcnt vmcnt(6)" ::: "memory"); // tile t+1 landed
            else          asm volatile("s_waitcnt vmcnt(0)" ::: "memory"); // drain tail
            blockbar();
        }
        bc = (bc >= 2) ? 0 : bc + 1;
    }

    // --- epilogue: C/D layout col=lane&15, row=q*4+r
#pragma unroll
    for (int i = 0; i < 4; ++i) {
#pragma unroll
        for (int j = 0; j < 4; ++j) {
            const int col = n0 + wn * 64 + j * 16 + fm;
            float bv = 0.f;
            if (EPI == EPI_BIAS) bv = bias[col];
#pragma unroll
            for (int r = 0; r < 4; ++r) {
                const int row = m0 + wm * 64 + i * 16 + q * 4 + r;
                float v = acc[i][j][r];
                if (EPI == EPI_THRESH) v = (fabsf(v) > 1e-3f) ? v : 0.f;
                if (EPI == EPI_BIAS) v += bv;
                C[(size_t)row * N + col] = (CT)v;
            }
        }
    }
}

// dispatch 2: h = thresh(xb @ Ub^T) [blocks 0..767, XCD-swizzled; 768%8==0 so
// the simple bijective swizzle is valid] and Wc = VTb @ Wt^T [blocks 768..785].
__global__ __launch_bounds__(512, 2)
void gemm_h_wc(const bf16_t* __restrict__ xb, const bf16_t* __restrict__ Ub,
               bf16_t* __restrict__ h,
               const bf16_t* __restrict__ VTb, const bf16_t* __restrict__ Wt,
               bf16_t* __restrict__ Wc)
{
    __shared__ __align__(16) bf16_t As[3 * 256 * 64];   // 96 KiB
    __shared__ __align__(16) bf16_t Bs[3 * 128 * 64];   // 48 KiB
    const int b = blockIdx.x;
    if (b < 768) {
        const int L = (b & 7) * 96 + (b >> 3);          // XCD-contiguous tiles
        gemm_tile<EPI_THRESH, bf16_t>(xb, Ub, h, nullptr,
                                      (L / 6) * BM, (L % 6) * BN, 768, 768, As, Bs);
    } else {
        const int b2 = b - 768;                          // 0..17
        gemm_tile<EPI_NONE, bf16_t>(VTb, Wt, Wc, nullptr,
                                    (b2 / 6) * BM, (b2 % 6) * BN, 768, 768, As, Bs);
    }
}

// dispatch 3: out = h @ Wc^T + bias (fp32 store)
__global__ __launch_bounds__(512, 2)
void gemm_out(const bf16_t* __restrict__ h, const bf16_t* __restrict__ Wc,
              float* __restrict__ out, const float* __restrict__ bias)
{
    __shared__ __align__(16) bf16_t As[3 * 256 * 64];
    __shared__ __align__(16) bf16_t Bs[3 * 128 * 64];
    const int b = blockIdx.x;
    const int L = (b & 7) * 96 + (b >> 3);
    gemm_tile<EPI_BIAS, float>(h, Wc, out, bias,
                               (L / 6) * BM, (L % 6) * BN, 768, 768, As, Bs);
}

// dispatch 1: all fp32->bf16 conversions + weight transpose in one kernel.
// blocks [0,24576): x cvt; [24576,25152): U; [25152,25728): VT; [25728,26304): w^T
__global__ __launch_bounds__(256)
void prep(const float* __restrict__ x, const float* __restrict__ U,
          const float* __restrict__ VT, const float* __restrict__ w,
          bf16_t* __restrict__ xb, bf16_t* __restrict__ Ub,
          bf16_t* __restrict__ VTb, bf16_t* __restrict__ Wt)
{
    __shared__ float tt[32][33];
    const int b = blockIdx.x;
    if (b < 25728) {
        const float* src; bf16_t* dst; int i;
        if (b < 24576)      { src = x;  dst = xb;  i = b * 256 + threadIdx.x; }
        else if (b < 25152) { src = U;  dst = Ub;  i = (b - 24576) * 256 + threadIdx.x; }
        else                { src = VT; dst = VTb; i = (b - 25152) * 256 + threadIdx.x; }
        const f32x4 v = ((const f32x4*)src)[i];
        bf16x4 o;
        o[0] = (bf16_t)v[0]; o[1] = (bf16_t)v[1];
        o[2] = (bf16_t)v[2]; o[3] = (bf16_t)v[3];
        ((bf16x4*)dst)[i] = o;
    } else {
        const int t = b - 25728;              // 0..575
        const int bx = (t % 24) * 32, by = (t / 24) * 32;
        const int tx = threadIdx.x & 31, ty = threadIdx.x >> 5;  // 32 x 8
#pragma unroll
        for (int i = 0; i < 32; i += 8)
            tt[ty + i][tx] = w[(size_t)(by + ty + i) * 768 + bx + tx];
        __syncthreads();
#pragma unroll
        for (int i = 0; i < 32; i += 8)
            Wt[(size_t)(bx + ty + i) * 768 + by + tx] = (bf16_t)tt[tx][ty + i];
    }
}

extern "C" void kernel_launch(void* const* d_in, const int* in_sizes, int n_in,
                              void* d_out, int out_size, void* d_ws, size_t ws_size,
                              hipStream_t stream)
{
    const float* x    = (const float*)d_in[0];   // (8,4096,768) fp32
    const float* w    = (const float*)d_in[1];   // (768,768) fp32
    const float* bias = (const float*)d_in[2];   // (768,) fp32
    const float* U    = (const float*)d_in[3];   // (768,768) fp32
    const float* VT   = (const float*)d_in[4];   // (768,768) fp32
    float* out = (float*)d_out;                  // (8,4096,768) fp32

    const int D = 768;
    const int M = 8 * 4096;                      // 32768
    const size_t MD = (size_t)M * D;
    const size_t DD = (size_t)D * D;

    char* ws = (char*)d_ws;
    bf16_t* xb  = (bf16_t*)ws;                         // MD bf16
    bf16_t* h   = (bf16_t*)(ws + MD * 2);              // MD bf16
    bf16_t* Ub  = (bf16_t*)(ws + MD * 4);              // DD
    bf16_t* VTb = (bf16_t*)(ws + MD * 4 + DD * 2);     // DD
    bf16_t* Wt  = (bf16_t*)(ws + MD * 4 + DD * 4);     // DD: weight^T
    bf16_t* Wc  = (bf16_t*)(ws + MD * 4 + DD * 6);     // DD: VT@weight

    // 1) conversions + transpose fused
    prep<<<26304, 256, 0, stream>>>(x, U, VT, w, xb, Ub, VTb, Wt);
    // 2) h = thresh(xb @ Ub^T)  +  Wc = (VT @ weight) in the same dispatch
    gemm_h_wc<<<768 + 18, 512, 0, stream>>>(xb, Ub, h, VTb, Wt, Wc);
    // 3) out = h @ Wc^T + bias  (== ((h @ W^T) @ VT^T) + bias)
    gemm_out<<<768, 512, 0, stream>>>(h, Wc, out, bias);
}